// Round 7
// baseline (306.987 us; speedup 1.0000x reference)
//
#include <hip/hip_runtime.h>

#define CLAMP_THR 0.9999999f

// 4-byte-aligned float4 (element base 9*e is only dword-aligned)
typedef float f4a __attribute__((ext_vector_type(4), aligned(4)));

__global__ void zero_loss_kernel(float* out) {
    if (threadIdx.x == 0) out[0] = 0.0f;
}

__device__ __forceinline__ void lds_fence() {
    // order ds_write -> ds_read within a wave, no block barrier needed
    __builtin_amdgcn_wave_barrier();
    asm volatile("s_waitcnt lgkmcnt(0)" ::: "memory");
    __builtin_amdgcn_wave_barrier();
}

template<bool USE_WS>
__global__ __launch_bounds__(256) void geodesic_tp_kernel(
    const float* __restrict__ Rrel,   // [N,3,3]
    const float* __restrict__ Rw1,    // [N,3,3]  R_w2c1
    const float* __restrict__ Rw2,    // [N,3,3]  R_w2c2
    float* __restrict__ out,          // [1 + 9N + 9N]
    float* __restrict__ ws,           // per-wave loss partials (USE_WS)
    int n)
{
    __shared__ float tp[4][576];      // per-wave transpose buffer (9216 B total)

    const int t    = threadIdx.x;
    const int lane = t & 63;
    const int w    = t >> 6;
    const int e    = blockIdx.x * 256 + t;        // this thread's element
    const int wbase = blockIdx.x * 256 + w * 64;  // wave's first element
    const bool full = (wbase + 64 <= n);          // all 64 lanes valid?

    float local_loss = 0.0f;
    float D1[9], D2[9];

    if (e < n) {
        const size_t b = (size_t)e * 9;
        float R[9], A[9], B[9];

        f4a v;
        v = *(const f4a*)(Rrel + b);     R[0]=v.x; R[1]=v.y; R[2]=v.z; R[3]=v.w;
        v = *(const f4a*)(Rrel + b + 4); R[4]=v.x; R[5]=v.y; R[6]=v.z; R[7]=v.w;
        R[8] = Rrel[b + 8];
        v = *(const f4a*)(Rw2 + b);      A[0]=v.x; A[1]=v.y; A[2]=v.z; A[3]=v.w;
        v = *(const f4a*)(Rw2 + b + 4);  A[4]=v.x; A[5]=v.y; A[6]=v.z; A[7]=v.w;
        A[8] = Rw2[b + 8];
        v = *(const f4a*)(Rw1 + b);      B[0]=v.x; B[1]=v.y; B[2]=v.z; B[3]=v.w;
        v = *(const f4a*)(Rw1 + b + 4);  B[4]=v.x; B[5]=v.y; B[6]=v.z; B[7]=v.w;
        B[8] = Rw1[b + 8];

        // M = R_rel^T @ R_w2c2 ; M[i][k] = sum_j R[j][i]*A[j][k]
        float M[9];
        #pragma unroll
        for (int i = 0; i < 3; ++i)
            #pragma unroll
            for (int k = 0; k < 3; ++k)
                M[3 * i + k] = R[i]     * A[k]
                             + R[3 + i] * A[3 + k]
                             + R[6 + i] * A[6 + k];
        float tr = 0.0f;
        #pragma unroll
        for (int j = 0; j < 9; ++j) tr += M[j] * B[j];

        float cosv = 0.5f * (tr - 1.0f);
        float cosc = fminf(fmaxf(cosv, -CLAMP_THR), CLAMP_THR);
        local_loss = acosf(cosc);
        float g = (fabsf(cosv) < CLAMP_THR)
                    ? (-0.5f / sqrtf(1.0f - cosc * cosc))
                    : 0.0f;

        #pragma unroll
        for (int j = 0; j < 9; ++j) D1[j] = g * M[j];
        // D2 = g * (R_rel @ R_w2c1); [i][k] = sum_j R[i][j]*B[j][k]
        #pragma unroll
        for (int i = 0; i < 3; ++i)
            #pragma unroll
            for (int k = 0; k < 3; ++k)
                D2[3 * i + k] = g * (R[3 * i]     * B[k]
                                   + R[3 * i + 1] * B[3 + k]
                                   + R[3 * i + 2] * B[6 + k]);
    }

    float* __restrict__ out1 = out + 1;
    float* __restrict__ out2 = out + 1 + (size_t)n * 9;

    if (full) {
        float* buf = tp[w];
        const size_t wb9 = (size_t)wbase * 9;

        // ---- d_R_w2c1: strided LDS write (2-way alias, free) -> coalesced store
        #pragma unroll
        for (int c = 0; c < 9; ++c) buf[9 * lane + c] = D1[c];
        lds_fence();
        #pragma unroll
        for (int j = 0; j < 9; ++j)
            out1[wb9 + 64 * j + lane] = buf[64 * j + lane];
        lds_fence();   // reads done before buffer reuse

        // ---- d_R_w2c2
        #pragma unroll
        for (int c = 0; c < 9; ++c) buf[9 * lane + c] = D2[c];
        lds_fence();
        #pragma unroll
        for (int j = 0; j < 9; ++j)
            out2[wb9 + 64 * j + lane] = buf[64 * j + lane];
    } else if (e < n) {
        // partial tail wave: direct per-thread stores
        const size_t b = (size_t)e * 9;
        #pragma unroll
        for (int j = 0; j < 9; ++j) out1[b + j] = D1[j];
        #pragma unroll
        for (int j = 0; j < 9; ++j) out2[b + j] = D2[j];
    }

    // ---- loss: wave shuffle reduce -> per-wave partial (no block barrier)
    #pragma unroll
    for (int off = 32; off > 0; off >>= 1)
        local_loss += __shfl_down(local_loss, off, 64);
    if (lane == 0) {
        const int gw = blockIdx.x * 4 + w;   // global wave id
        if (USE_WS) ws[gw] = local_loss;
        else if (local_loss != 0.0f) atomicAdd(out, local_loss);
    }
}

__global__ __launch_bounds__(1024) void reduce_loss_kernel(
    const float* __restrict__ ws, int nw, float* __restrict__ out)
{
    __shared__ float wsum[16];
    const int t = threadIdx.x;
    float s = 0.0f;
    for (int i = t; i < nw; i += 1024) s += ws[i];
    #pragma unroll
    for (int off = 32; off > 0; off >>= 1)
        s += __shfl_down(s, off, 64);
    if ((t & 63) == 0) wsum[t >> 6] = s;
    __syncthreads();
    if (t == 0) {
        float tot = 0.0f;
        #pragma unroll
        for (int i = 0; i < 16; ++i) tot += wsum[i];
        out[0] = tot;
    }
}

extern "C" void kernel_launch(void* const* d_in, const int* in_sizes, int n_in,
                              void* d_out, int out_size, void* d_ws, size_t ws_size,
                              hipStream_t stream) {
    const float* Rrel = (const float*)d_in[0];
    const float* Rw1  = (const float*)d_in[1];
    const float* Rw2  = (const float*)d_in[2];
    float* out = (float*)d_out;
    const int n  = in_sizes[0] / 9;
    const int nb = (n + 255) / 256;
    const int nw = nb * 4;

    if (ws_size >= (size_t)nw * sizeof(float)) {
        geodesic_tp_kernel<true><<<nb, 256, 0, stream>>>(
            Rrel, Rw1, Rw2, out, (float*)d_ws, n);
        reduce_loss_kernel<<<1, 1024, 0, stream>>>((const float*)d_ws, nw, out);
    } else {
        zero_loss_kernel<<<1, 64, 0, stream>>>(out);
        geodesic_tp_kernel<false><<<nb, 256, 0, stream>>>(
            Rrel, Rw1, Rw2, out, nullptr, n);
    }
}

// Round 8
// 304.895 us; speedup vs baseline: 1.0069x; 1.0069x over previous
//
#include <hip/hip_runtime.h>

#define CLAMP_THR 0.9999999f

// 4-byte-aligned float4 (element base 9*e is only dword-aligned)
typedef float f4a __attribute__((ext_vector_type(4), aligned(4)));

__global__ void zero_loss_kernel(float* out) {
    if (threadIdx.x == 0) out[0] = 0.0f;
}

// Compute one element given its 27 inputs already in registers.
// Returns acos loss; writes the two 9-float gradients directly.
__device__ __forceinline__ float compute_store(
    const float R[9], const float A[9], const float B[9],
    float* __restrict__ o1, float* __restrict__ o2)
{
    // M = R_rel^T @ R_w2c2 ; M[i][k] = sum_j R[j][i]*A[j][k]
    float M[9];
    #pragma unroll
    for (int i = 0; i < 3; ++i)
        #pragma unroll
        for (int k = 0; k < 3; ++k)
            M[3 * i + k] = R[i]     * A[k]
                         + R[3 + i] * A[3 + k]
                         + R[6 + i] * A[6 + k];
    float tr = 0.0f;
    #pragma unroll
    for (int j = 0; j < 9; ++j) tr += M[j] * B[j];

    const float cosv = 0.5f * (tr - 1.0f);
    const float cosc = fminf(fmaxf(cosv, -CLAMP_THR), CLAMP_THR);
    const float g = (fabsf(cosv) < CLAMP_THR)
                      ? (-0.5f / sqrtf(1.0f - cosc * cosc))
                      : 0.0f;

    f4a s;
    s.x = g*M[0]; s.y = g*M[1]; s.z = g*M[2]; s.w = g*M[3];
    *(f4a*)(o1) = s;
    s.x = g*M[4]; s.y = g*M[5]; s.z = g*M[6]; s.w = g*M[7];
    *(f4a*)(o1 + 4) = s;
    o1[8] = g*M[8];

    float D[9];
    #pragma unroll
    for (int i = 0; i < 3; ++i)
        #pragma unroll
        for (int k = 0; k < 3; ++k)
            D[3 * i + k] = g * (R[3 * i]     * B[k]
                              + R[3 * i + 1] * B[3 + k]
                              + R[3 * i + 2] * B[6 + k]);
    s.x = D[0]; s.y = D[1]; s.z = D[2]; s.w = D[3];
    *(f4a*)(o2) = s;
    s.x = D[4]; s.y = D[5]; s.z = D[6]; s.w = D[7];
    *(f4a*)(o2 + 4) = s;
    o2[8] = D[8];

    return acosf(cosc);
}

template<bool USE_WS>
__global__ __launch_bounds__(256) void geodesic_ilp2_kernel(
    const float* __restrict__ Rrel,   // [N,3,3]
    const float* __restrict__ Rw1,    // [N,3,3]  R_w2c1
    const float* __restrict__ Rw2,    // [N,3,3]  R_w2c2
    float* __restrict__ out,          // [1 + 9N + 9N]
    float* __restrict__ ws,           // per-wave loss partials (USE_WS)
    int n)
{
    const int t    = threadIdx.x;
    const int lane = t & 63;
    const int w    = t >> 6;
    const int e0   = blockIdx.x * 512 + t;        // first element
    const int e1   = e0 + 256;                    // second element

    float local_loss = 0.0f;
    float* __restrict__ out1 = out + 1;
    float* __restrict__ out2 = out + 1 + (size_t)n * 9;

    // ---- issue ALL independent loads for both elements up front ----
    f4a r0a, r1a, a0a, a1a, b0a, b1a;  float r2a, a2a, b2a;
    f4a r0b, r1b, a0b, a1b, b0b, b1b;  float r2b, a2b, b2b;
    const bool va = (e0 < n), vb = (e1 < n);

    if (va) {
        const size_t b = (size_t)e0 * 9;
        r0a = *(const f4a*)(Rrel + b); r1a = *(const f4a*)(Rrel + b + 4); r2a = Rrel[b + 8];
        a0a = *(const f4a*)(Rw2  + b); a1a = *(const f4a*)(Rw2  + b + 4); a2a = Rw2[b + 8];
        b0a = *(const f4a*)(Rw1  + b); b1a = *(const f4a*)(Rw1  + b + 4); b2a = Rw1[b + 8];
    }
    if (vb) {
        const size_t b = (size_t)e1 * 9;
        r0b = *(const f4a*)(Rrel + b); r1b = *(const f4a*)(Rrel + b + 4); r2b = Rrel[b + 8];
        a0b = *(const f4a*)(Rw2  + b); a1b = *(const f4a*)(Rw2  + b + 4); a2b = Rw2[b + 8];
        b0b = *(const f4a*)(Rw1  + b); b1b = *(const f4a*)(Rw1  + b + 4); b2b = Rw1[b + 8];
    }

    if (va) {
        const size_t b = (size_t)e0 * 9;
        float R[9] = {r0a.x,r0a.y,r0a.z,r0a.w, r1a.x,r1a.y,r1a.z,r1a.w, r2a};
        float A[9] = {a0a.x,a0a.y,a0a.z,a0a.w, a1a.x,a1a.y,a1a.z,a1a.w, a2a};
        float B[9] = {b0a.x,b0a.y,b0a.z,b0a.w, b1a.x,b1a.y,b1a.z,b1a.w, b2a};
        local_loss += compute_store(R, A, B, out1 + b, out2 + b);
    }
    if (vb) {
        const size_t b = (size_t)e1 * 9;
        float R[9] = {r0b.x,r0b.y,r0b.z,r0b.w, r1b.x,r1b.y,r1b.z,r1b.w, r2b};
        float A[9] = {a0b.x,a0b.y,a0b.z,a0b.w, a1b.x,a1b.y,a1b.z,a1b.w, a2b};
        float B[9] = {b0b.x,b0b.y,b0b.z,b0b.w, b1b.x,b1b.y,b1b.z,b1b.w, b2b};
        local_loss += compute_store(R, A, B, out1 + b, out2 + b);
    }

    // ---- loss: wave shuffle reduce -> per-wave partial (no block barrier) ----
    #pragma unroll
    for (int off = 32; off > 0; off >>= 1)
        local_loss += __shfl_down(local_loss, off, 64);
    if (lane == 0) {
        const int gw = blockIdx.x * 4 + w;
        if (USE_WS) ws[gw] = local_loss;
        else if (local_loss != 0.0f) atomicAdd(out, local_loss);
    }
}

__global__ __launch_bounds__(1024) void reduce_loss_kernel(
    const float* __restrict__ ws, int nw, float* __restrict__ out)
{
    __shared__ float wsum[16];
    const int t = threadIdx.x;
    float s = 0.0f;
    for (int i = t; i < nw; i += 1024) s += ws[i];
    #pragma unroll
    for (int off = 32; off > 0; off >>= 1)
        s += __shfl_down(s, off, 64);
    if ((t & 63) == 0) wsum[t >> 6] = s;
    __syncthreads();
    if (t == 0) {
        float tot = 0.0f;
        #pragma unroll
        for (int i = 0; i < 16; ++i) tot += wsum[i];
        out[0] = tot;
    }
}

extern "C" void kernel_launch(void* const* d_in, const int* in_sizes, int n_in,
                              void* d_out, int out_size, void* d_ws, size_t ws_size,
                              hipStream_t stream) {
    const float* Rrel = (const float*)d_in[0];
    const float* Rw1  = (const float*)d_in[1];
    const float* Rw2  = (const float*)d_in[2];
    float* out = (float*)d_out;
    const int n  = in_sizes[0] / 9;
    const int nb = (n + 511) / 512;   // 2 elements per thread
    const int nw = nb * 4;

    if (ws_size >= (size_t)nw * sizeof(float)) {
        geodesic_ilp2_kernel<true><<<nb, 256, 0, stream>>>(
            Rrel, Rw1, Rw2, out, (float*)d_ws, n);
        reduce_loss_kernel<<<1, 1024, 0, stream>>>((const float*)d_ws, nw, out);
    } else {
        zero_loss_kernel<<<1, 64, 0, stream>>>(out);
        geodesic_ilp2_kernel<false><<<nb, 256, 0, stream>>>(
            Rrel, Rw1, Rw2, out, nullptr, n);
    }
}